// Round 4
// baseline (148.095 us; speedup 1.0000x reference)
//
#include <hip/hip_runtime.h>
#include <math.h>

// Output = segment_softmax over logits that depend ONLY on the inputs part of
// combined @ W_k: the agg(segment-mean MLP) contribution is constant within a
// segment and cancels exactly in the segment softmax (shift invariance).
// wx[d][h] = sum_j Wk[d, h*64+j]*Wq[h,j] / 8;  logit[n,h] = x[n,:].wx[:,h];
// per-segment softmax; out[h*N + n].
//
// Round 4: 4-lanes-per-row cooperative loads (float2 at lane-interleaved
// offsets) so each global load instruction touches ~16 cache lines instead of
// 64 -> 4x fewer L1 lookups per byte. Intra-quad shfl butterfly distributes
// head-h logit to lane 4g+h; per-head reductions use shfl_xor {4,8,16,32}.

#define NROWS 500000
#define DIM 40
#define NSEG 2048
#define DOTD 64
#define NH 4
#define BLOCK 256
#define SEG_PER_BLOCK 4      // 4 waves/block, one segment per wave
#define CACHE_IT 24          // 24*16 = 384 rows fast path (stat max ~310)
#define NEG_INF (-3.0e38f)

// ---- prep: segment bounds (with gap fill for empty segments) + wx fold ----
__global__ __launch_bounds__(BLOCK) void prep_kernel(
    const int* __restrict__ seg,    // [N], sorted
    const float* __restrict__ Wk,   // [168, 256]
    const float* __restrict__ Wq,   // [4, 64]
    int* __restrict__ seg_start,    // [NSEG]
    int* __restrict__ seg_end,      // [NSEG]
    float* __restrict__ wxg)        // [DIM*NH], layout d*4+h
{
    const int tid = (int)threadIdx.x;
    const int n = (int)(blockIdx.x * BLOCK + tid);

    if (blockIdx.x == 0 && tid < DIM * NH) {
        const int d = tid >> 2;
        const int h = tid & 3;
        const float* wkp = Wk + d * (NH * DOTD) + h * DOTD;
        const float* wqp = Wq + h * DOTD;
        float acc = 0.f;
        #pragma unroll
        for (int j = 0; j < DOTD; ++j) acc += wkp[j] * wqp[j];
        wxg[tid] = acc * 0.125f;  // fold 1/sqrt(64)
    }

    if (n < NROWS) {
        const int s = seg[n];
        if (n == 0) {
            seg_start[s] = 0;
            for (int t = 0; t < s; ++t) { seg_start[t] = 0; seg_end[t] = 0; }
        } else {
            const int sp = seg[n - 1];
            if (sp != s) {
                seg_start[s] = n;
                seg_end[sp] = n;
                for (int t = sp + 1; t < s; ++t) { seg_start[t] = n; seg_end[t] = n; }
            }
        }
        if (n == NROWS - 1) {
            seg_end[s] = NROWS;
            for (int t = s + 1; t < NSEG; ++t) { seg_start[t] = NROWS; seg_end[t] = NROWS; }
        }
    }
}

// Compute head-(lane&3) logit for row (start + r) using the 4-lane group.
// Returns NEG_INF-ish garbage only if !valid (caller guards).
__device__ __forceinline__ float quad_logit(
    const float* __restrict__ x, const float (*wx)[NH],
    int n, int jj, bool valid)
{
    float acc[NH] = {0.f, 0.f, 0.f, 0.f};
    if (valid) {
        const float2* p = (const float2*)(x + (size_t)n * DIM);
        #pragma unroll
        for (int k = 0; k < 5; ++k) {
            const float2 v = p[jj + 4 * k];
            const int d0 = 2 * (jj + 4 * k);
            #pragma unroll
            for (int h = 0; h < NH; ++h) {
                acc[h] += v.x * wx[d0][h] + v.y * wx[d0 + 1][h];
            }
        }
    }
    // intra-quad butterfly: full dot per head in every lane of the quad
    #pragma unroll
    for (int h = 0; h < NH; ++h) {
        acc[h] += __shfl_xor(acc[h], 1, 64);
        acc[h] += __shfl_xor(acc[h], 2, 64);
    }
    // select own head
    const float t0 = (jj & 1) ? acc[1] : acc[0];
    const float t1 = (jj & 1) ? acc[3] : acc[2];
    return (jj & 2) ? t1 : t0;
}

// ---- main: one wave (64 lanes) per segment, 4 lanes per row ----
__global__ __launch_bounds__(BLOCK) void seg_attn_kernel(
    const float* __restrict__ x,          // [N, 40]
    const int* __restrict__ seg_start,
    const int* __restrict__ seg_end,
    const float* __restrict__ wxg,        // [DIM*NH]
    float* __restrict__ out)              // [4, N]
{
    __shared__ float wx[DIM][NH];

    const int tid = (int)threadIdx.x;
    if (tid < DIM * NH) wx[tid >> 2][tid & 3] = wxg[tid];
    __syncthreads();

    const int lane = tid & 63;
    const int g = lane >> 2;       // row within 16-row tile
    const int jj = lane & 3;       // head
    const int s = (int)blockIdx.x * SEG_PER_BLOCK + (tid >> 6);
    const int start = seg_start[s];
    const int end = seg_end[s];
    const int rows = end - start;
    if (rows <= 0) return;               // wave-uniform exit
    const int iters = (rows + 15) >> 4;

    // ---- pass 1: logits + per-lane max ----
    float cache[CACHE_IT];
    float lmax = NEG_INF;
    for (int it = 0; it < iters; ++it) {
        const int r = it * 16 + g;
        const bool valid = (r < rows);
        float l = quad_logit(x, wx, start + r, jj, valid);
        if (!valid) l = NEG_INF;
        if (it < CACHE_IT) cache[it] = l;
        lmax = fmaxf(lmax, l);
    }

    // ---- per-head wave max (offsets 4..32 keep lane&3 invariant) ----
    float m = lmax;
    #pragma unroll
    for (int off = 4; off <= 32; off <<= 1) m = fmaxf(m, __shfl_xor(m, off, 64));

    // ---- pass 2: exp + per-head wave sum; cache becomes exp(l-m) ----
    float lsum = 0.f;
    for (int it = 0; it < iters; ++it) {
        float e;
        if (it < CACHE_IT) {
            e = __expf(cache[it] - m);   // NEG_INF -> 0
            cache[it] = e;
        } else {  // fallback: segment longer than 384 rows
            const int r = it * 16 + g;
            const bool valid = (r < rows);
            float l = quad_logit(x, wx, start + r, jj, valid);
            e = valid ? __expf(l - m) : 0.f;
        }
        lsum += e;
    }
    float v = lsum;
    #pragma unroll
    for (int off = 4; off <= 32; off <<= 1) v += __shfl_xor(v, off, 64);
    const float rden = 1.0f / v;

    // ---- pass 3: write normalized outputs ----
    for (int it = 0; it < iters; ++it) {
        const int r = it * 16 + g;
        if (r >= rows) continue;
        float e;
        if (it < CACHE_IT) {
            e = cache[it];
        } else {
            float l = quad_logit(x, wx, start + r, jj, true);
            e = __expf(l - m);
        }
        out[(size_t)jj * NROWS + start + r] = e * rden;
    }
}

extern "C" void kernel_launch(void* const* d_in, const int* in_sizes, int n_in,
                              void* d_out, int out_size, void* d_ws, size_t ws_size,
                              hipStream_t stream) {
    const float* x  = (const float*)d_in[0];
    const int* seg  = (const int*)d_in[1];
    const float* Wk = (const float*)d_in[11];
    const float* Wq = (const float*)d_in[12];
    float* out = (float*)d_out;

    int* seg_start = (int*)d_ws;                  // [NSEG]
    int* seg_end   = seg_start + NSEG;            // [NSEG]
    float* wxg     = (float*)(seg_end + NSEG);    // [DIM*NH]

    hipLaunchKernelGGL(prep_kernel, dim3((NROWS + BLOCK - 1) / BLOCK), dim3(BLOCK),
                       0, stream, seg, Wk, Wq, seg_start, seg_end, wxg);
    hipLaunchKernelGGL(seg_attn_kernel, dim3(NSEG / SEG_PER_BLOCK), dim3(BLOCK),
                       0, stream, x, seg_start, seg_end, wxg, out);
}